// Round 1
// baseline (531.147 us; speedup 1.0000x reference)
//
#include <hip/hip_runtime.h>
#include <hip/hip_bf16.h>

#define IN_F   1024
#define OUT_F  1024
#define NBASIS 8
#define KDIM   (IN_F + IN_F * NBASIS)   // 9216
#define BM 128
#define BN 128
#define BK 64
#define KT      (KDIM / BK)             // 144
#define BASE_KT (IN_F / BK)             // 16

typedef __attribute__((ext_vector_type(8))) short          bf16x8;
typedef __attribute__((ext_vector_type(8))) unsigned short u16x8;
typedef __attribute__((ext_vector_type(4))) float          f32x4;

// ---- helpers -------------------------------------------------------------
__device__ __forceinline__ unsigned short bfr(float f) {
    // round-to-nearest-even f32 -> bf16 (finite inputs only)
    unsigned u = __float_as_uint(f);
    unsigned r = (u + 0x7FFFu + ((u >> 16) & 1u)) >> 16;
    return (unsigned short)r;
}
__device__ __forceinline__ float silu_f(float v) { return v / (1.0f + __expf(-v)); }

// monotone float<->uint key for atomic min/max
__device__ __forceinline__ unsigned fkey(float f) {
    unsigned u = __float_as_uint(f);
    return u ^ ((u >> 31) ? 0xFFFFFFFFu : 0x80000000u);
}
__device__ __forceinline__ float fkey_dec(unsigned u) {
    unsigned b = (u >> 31) ? (u ^ 0x80000000u) : ~u;
    return __uint_as_float(b);
}

// ---- kernel 1: global min/max of x --------------------------------------
__global__ void k_minmax(const float* __restrict__ x, unsigned* __restrict__ mm, int n4) {
    int tid    = blockIdx.x * blockDim.x + threadIdx.x;
    int stride = gridDim.x * blockDim.x;
    const float4* x4 = (const float4*)x;
    float mx  = -3.402823466e+38f;   // max(x)
    float mxn = -3.402823466e+38f;   // max(-x)
    for (int i = tid; i < n4; i += stride) {
        float4 v = x4[i];
        mx  = fmaxf(mx,  fmaxf(fmaxf(v.x, v.y), fmaxf(v.z, v.w)));
        mxn = fmaxf(mxn, -fminf(fminf(v.x, v.y), fminf(v.z, v.w)));
    }
    #pragma unroll
    for (int off = 32; off; off >>= 1) {
        mx  = fmaxf(mx,  __shfl_down(mx,  off));
        mxn = fmaxf(mxn, __shfl_down(mxn, off));
    }
    __shared__ float smx[4], smn[4];
    int lane = threadIdx.x & 63, wid = threadIdx.x >> 6;
    if (lane == 0) { smx[wid] = mx; smn[wid] = mxn; }
    __syncthreads();
    if (threadIdx.x == 0) {
        #pragma unroll
        for (int w = 1; w < 4; ++w) { mx = fmaxf(mx, smx[w]); mxn = fmaxf(mxn, smn[w]); }
        atomicMax(&mm[0], fkey(mx));
        atomicMax(&mm[1], fkey(mxn));
    }
}

// ---- kernel 2: build combined bf16 weight Wc[OUT_F][KDIM] ----------------
// Wc[o][k] = base_weight[o][k]                         for k < 1024
//          = spline_weight[o][i][j] * scaler[o][i]     for k = 1024 + i*8 + j
__global__ void k_prepw(const float* __restrict__ bw, const float* __restrict__ sw,
                        const float* __restrict__ sc, unsigned short* __restrict__ Wc) {
    int t = blockIdx.x * blockDim.x + threadIdx.x;     // t = o*1024 + i
    int o = t >> 10, i = t & 1023;
    // base part: one scalar each
    Wc[(size_t)o * KDIM + i] = bfr(bw[t]);
    // spline part: 8 values
    float s = sc[t];
    const float4* swv = (const float4*)(sw + (size_t)t * 8);
    float4 a = swv[0], b = swv[1];
    u16x8 o8;
    o8[0] = bfr(a.x * s); o8[1] = bfr(a.y * s); o8[2] = bfr(a.z * s); o8[3] = bfr(a.w * s);
    o8[4] = bfr(b.x * s); o8[5] = bfr(b.y * s); o8[6] = bfr(b.z * s); o8[7] = bfr(b.w * s);
    *(u16x8*)(Wc + (size_t)o * KDIM + IN_F + i * 8) = o8;
}

// ---- kernel 3: fused GEMM  out = A @ Wc^T  (A computed on the fly) -------
__global__ __launch_bounds__(256, 2)
void k_gemm(const float* __restrict__ x, const unsigned short* __restrict__ Wc,
            const unsigned* __restrict__ mm, float* __restrict__ out) {
    __shared__ unsigned short As[BM * BK];   // [row][chunk-of-8, XOR-swizzled]
    __shared__ unsigned short Bs[BN * BK];

    const int t  = threadIdx.x;
    const int bM = blockIdx.x >> 3;
    const int bN = blockIdx.x & 7;

    const float xmax  = fkey_dec(mm[0]);
    const float xmin  = -fkey_dec(mm[1]);
    const float scale = 2.0f / (xmax - xmin + 1e-8f);

    const int lane = t & 63, wid = t >> 6;
    const int wr = (wid >> 1) * 64, wc = (wid & 1) * 64;

    // staging roles: 2 threads per row; rr in [0,128), kh in {0,1}
    const int rr = t >> 1, kh = t & 1;
    const float*          xrow = x  + (size_t)(bM * BM + rr) * IN_F;
    const unsigned short* wrow = Wc + (size_t)(bN * BN + rr) * KDIM;

    f32x4 acc[4][4] = {};

    for (int kt = 0; kt < KT; ++kt) {
        __syncthreads();
        // ---- stage B tile: Wc rows [bN*128 .. +128), cols [kt*64 .. +64)
        {
            const u16x8* src = (const u16x8*)(wrow + kt * BK + kh * 32);
            #pragma unroll
            for (int q = 0; q < 4; ++q) {
                u16x8 v = src[q];
                int c = (kh * 4 + q) ^ (rr & 7);
                *(u16x8*)&Bs[rr * BK + c * 8] = v;
            }
        }
        // ---- stage A tile (computed)
        if (kt < BASE_KT) {
            // silu region: cols are features kt*64 .. +64
            const float* xp = xrow + kt * BK + kh * 32;
            #pragma unroll
            for (int q = 0; q < 4; ++q) {
                float4 v0 = *(const float4*)(xp + q * 8);
                float4 v1 = *(const float4*)(xp + q * 8 + 4);
                u16x8 o8;
                o8[0] = bfr(silu_f(v0.x)); o8[1] = bfr(silu_f(v0.y));
                o8[2] = bfr(silu_f(v0.z)); o8[3] = bfr(silu_f(v0.w));
                o8[4] = bfr(silu_f(v1.x)); o8[5] = bfr(silu_f(v1.y));
                o8[6] = bfr(silu_f(v1.z)); o8[7] = bfr(silu_f(v1.w));
                int c = (kh * 4 + q) ^ (rr & 7);
                *(u16x8*)&As[rr * BK + c * 8] = o8;
            }
        } else {
            // spline region: 8 features per K-tile, 8 basis values per feature
            const int f0 = (kt - BASE_KT) * 8 + kh * 4;
            float4 v = *(const float4*)(xrow + f0);
            #pragma unroll
            for (int q = 0; q < 4; ++q) {
                float xv = (q == 0) ? v.x : (q == 1) ? v.y : (q == 2) ? v.z : v.w;
                float xn = (xv - xmin) * scale - 1.0f;
                float u  = (xn + 2.2f) * 2.5f;       // knot spacing h=0.4, t0=-2.2
                int   iv = (int)floorf(u);
                iv = iv < 3 ? 3 : (iv > 7 ? 7 : iv);
                float tt = u - (float)iv;
                float s1 = 1.0f - tt;
                float t2 = tt * tt, t3 = t2 * tt;
                float n0 = s1 * s1 * s1 * (1.0f / 6.0f);
                float n1 = (3.0f * t3 - 6.0f * t2 + 4.0f) * (1.0f / 6.0f);
                float n2 = (-3.0f * t3 + 3.0f * t2 + 3.0f * tt + 1.0f) * (1.0f / 6.0f);
                float n3 = t3 * (1.0f / 6.0f);
                int j0 = iv - 3;                     // first nonzero slot, 0..4
                u16x8 o8;
                #pragma unroll
                for (int s = 0; s < 8; ++s) {
                    int d = s - j0;
                    float val = (d == 0) ? n0 : (d == 1) ? n1 : (d == 2) ? n2 : (d == 3) ? n3 : 0.0f;
                    o8[s] = bfr(val);
                }
                int c = (kh * 4 + q) ^ (rr & 7);
                *(u16x8*)&As[rr * BK + c * 8] = o8;
            }
        }
        __syncthreads();

        // ---- fragments + MFMA
        bf16x8 af[4][2];
        #pragma unroll
        for (int mi = 0; mi < 4; ++mi) {
            int row = wr + mi * 16 + (lane & 15);
            int rb  = row & 7;
            #pragma unroll
            for (int ks = 0; ks < 2; ++ks) {
                int c = (ks * 4 + (lane >> 4)) ^ rb;
                af[mi][ks] = *(const bf16x8*)&As[row * BK + c * 8];
            }
        }
        #pragma unroll
        for (int ni = 0; ni < 4; ++ni) {
            int col = wc + ni * 16 + (lane & 15);
            int cb  = col & 7;
            bf16x8 b0 = *(const bf16x8*)&Bs[col * BK + (((lane >> 4)) ^ cb) * 8];
            bf16x8 b1 = *(const bf16x8*)&Bs[col * BK + ((4 + (lane >> 4)) ^ cb) * 8];
            #pragma unroll
            for (int mi = 0; mi < 4; ++mi) {
                acc[mi][ni] = __builtin_amdgcn_mfma_f32_16x16x32_bf16(af[mi][0], b0, acc[mi][ni], 0, 0, 0);
                acc[mi][ni] = __builtin_amdgcn_mfma_f32_16x16x32_bf16(af[mi][1], b1, acc[mi][ni], 0, 0, 0);
            }
        }
    }

    // ---- epilogue: C/D layout col=lane&15, row=(lane>>4)*4+reg
    #pragma unroll
    for (int mi = 0; mi < 4; ++mi) {
        #pragma unroll
        for (int ni = 0; ni < 4; ++ni) {
            #pragma unroll
            for (int reg = 0; reg < 4; ++reg) {
                int row = wr + mi * 16 + (lane >> 4) * 4 + reg;
                int col = wc + ni * 16 + (lane & 15);
                out[(size_t)(bM * BM + row) * OUT_F + bN * BN + col] = acc[mi][ni][reg];
            }
        }
    }
}

// ---- launch --------------------------------------------------------------
extern "C" void kernel_launch(void* const* d_in, const int* in_sizes, int n_in,
                              void* d_out, int out_size, void* d_ws, size_t ws_size,
                              hipStream_t stream) {
    const float* x  = (const float*)d_in[0];
    // d_in[1] = grid (uniform knots, closed form used instead)
    const float* bw = (const float*)d_in[2];
    const float* sw = (const float*)d_in[3];
    const float* sc = (const float*)d_in[4];
    float* out = (float*)d_out;

    unsigned*       mm = (unsigned*)d_ws;
    unsigned short* Wc = (unsigned short*)((char*)d_ws + 512);   // 1024*9216 bf16 = 18.9 MB

    const int batch = in_sizes[0] / IN_F;   // 8192
    const int n4    = in_sizes[0] / 4;

    hipMemsetAsync(d_ws, 0, 8, stream);                       // init atomic keys
    k_minmax<<<1024, 256, 0, stream>>>(x, mm, n4);
    k_prepw<<<(OUT_F * IN_F) / 256, 256, 0, stream>>>(bw, sw, sc, Wc);
    k_gemm<<<dim3((batch / BM) * (OUT_F / BN)), 256, 0, stream>>>(x, Wc, mm, out);
}

// Round 2
// 367.776 us; speedup vs baseline: 1.4442x; 1.4442x over previous
//
#include <hip/hip_runtime.h>
#include <hip/hip_bf16.h>

#define IN_F   1024
#define OUT_F  1024
#define NBASIS 8
#define KDIM   (IN_F + IN_F * NBASIS)   // 9216
#define BM 128
#define BN 128
#define BK 64
#define KT      (KDIM / BK)             // 144
#define BASE_KT (IN_F / BK)             // 16

typedef __attribute__((ext_vector_type(8))) short          bf16x8;
typedef __attribute__((ext_vector_type(8))) unsigned short u16x8;
typedef __attribute__((ext_vector_type(4))) float          f32x4;

typedef const __attribute__((address_space(1))) void gas_t;
typedef __attribute__((address_space(3))) void las_t;
#define GLD16(g, l) __builtin_amdgcn_global_load_lds((gas_t*)(g), (las_t*)(l), 16, 0, 0)

// ---- helpers -------------------------------------------------------------
__device__ __forceinline__ unsigned short bfr(float f) {
    unsigned u = __float_as_uint(f);
    unsigned r = (u + 0x7FFFu + ((u >> 16) & 1u)) >> 16;
    return (unsigned short)r;
}
__device__ __forceinline__ float silu_f(float v) { return v / (1.0f + __expf(-v)); }

__device__ __forceinline__ unsigned fkey(float f) {
    unsigned u = __float_as_uint(f);
    return u ^ ((u >> 31) ? 0xFFFFFFFFu : 0x80000000u);
}
__device__ __forceinline__ float fkey_dec(unsigned u) {
    unsigned b = (u >> 31) ? (u ^ 0x80000000u) : ~u;
    return __uint_as_float(b);
}

// spline basis (uniform cubic, closed form — verified round 1)
__device__ __forceinline__ void spline8(float xv, float xmin, float scale, u16x8* o8p) {
    float xn = (xv - xmin) * scale - 1.0f;
    float u  = (xn + 2.2f) * 2.5f;       // h=0.4, t0=-2.2
    int   iv = (int)floorf(u);
    iv = iv < 3 ? 3 : (iv > 7 ? 7 : iv);
    float tt = u - (float)iv;
    float s1 = 1.0f - tt;
    float t2 = tt * tt, t3 = t2 * tt;
    float n0 = s1 * s1 * s1 * (1.0f / 6.0f);
    float n1 = (3.0f * t3 - 6.0f * t2 + 4.0f) * (1.0f / 6.0f);
    float n2 = (-3.0f * t3 + 3.0f * t2 + 3.0f * tt + 1.0f) * (1.0f / 6.0f);
    float n3 = t3 * (1.0f / 6.0f);
    int j0 = iv - 3;
    u16x8 o8;
    #pragma unroll
    for (int s = 0; s < 8; ++s) {
        int d = s - j0;
        float val = (d == 0) ? n0 : (d == 1) ? n1 : (d == 2) ? n2 : (d == 3) ? n3 : 0.0f;
        o8[s] = bfr(val);
    }
    *o8p = o8;
}

// ---- kernel 1: global min/max of x --------------------------------------
__global__ void k_minmax(const float* __restrict__ x, unsigned* __restrict__ mm, int n4) {
    int tid    = blockIdx.x * blockDim.x + threadIdx.x;
    int stride = gridDim.x * blockDim.x;
    const float4* x4 = (const float4*)x;
    float mx  = -3.402823466e+38f;
    float mxn = -3.402823466e+38f;
    for (int i = tid; i < n4; i += stride) {
        float4 v = x4[i];
        mx  = fmaxf(mx,  fmaxf(fmaxf(v.x, v.y), fmaxf(v.z, v.w)));
        mxn = fmaxf(mxn, -fminf(fminf(v.x, v.y), fminf(v.z, v.w)));
    }
    #pragma unroll
    for (int off = 32; off; off >>= 1) {
        mx  = fmaxf(mx,  __shfl_down(mx,  off));
        mxn = fmaxf(mxn, __shfl_down(mxn, off));
    }
    __shared__ float smx[4], smn[4];
    int lane = threadIdx.x & 63, wid = threadIdx.x >> 6;
    if (lane == 0) { smx[wid] = mx; smn[wid] = mxn; }
    __syncthreads();
    if (threadIdx.x == 0) {
        #pragma unroll
        for (int w = 1; w < 4; ++w) { mx = fmaxf(mx, smx[w]); mxn = fmaxf(mxn, smn[w]); }
        atomicMax(&mm[0], fkey(mx));
        atomicMax(&mm[1], fkey(mxn));
    }
}

// ---- kernel 2: build combined bf16 weight Wc[OUT_F][KDIM] ----------------
__global__ void k_prepw(const float* __restrict__ bw, const float* __restrict__ sw,
                        const float* __restrict__ sc, unsigned short* __restrict__ Wc) {
    int t = blockIdx.x * blockDim.x + threadIdx.x;     // t = o*1024 + i
    int o = t >> 10, i = t & 1023;
    Wc[(size_t)o * KDIM + i] = bfr(bw[t]);
    float s = sc[t];
    const float4* swv = (const float4*)(sw + (size_t)t * 8);
    float4 a = swv[0], b = swv[1];
    u16x8 o8;
    o8[0] = bfr(a.x * s); o8[1] = bfr(a.y * s); o8[2] = bfr(a.z * s); o8[3] = bfr(a.w * s);
    o8[4] = bfr(b.x * s); o8[5] = bfr(b.y * s); o8[6] = bfr(b.z * s); o8[7] = bfr(b.w * s);
    *(u16x8*)(Wc + (size_t)o * KDIM + IN_F + i * 8) = o8;
}

// ---- kernel 3: build bf16 A-matrix Ac[batch][KDIM] -----------------------
// Ac[r][k] = silu(x[r][k])        k < 1024
//          = basis_j(xn[r][i])    k = 1024 + i*8 + j
__global__ void k_build_a(const float* __restrict__ x, const unsigned* __restrict__ mm,
                          unsigned short* __restrict__ Ac) {
    int t = blockIdx.x * blockDim.x + threadIdx.x;   // t = row*1024 + i
    int row = t >> 10, i = t & 1023;
    const float xmax  = fkey_dec(mm[0]);
    const float xmin  = -fkey_dec(mm[1]);
    const float scale = 2.0f / (xmax - xmin + 1e-8f);
    float xv = x[t];
    size_t rb = (size_t)row * KDIM;
    Ac[rb + i] = bfr(silu_f(xv));
    u16x8 o8;
    spline8(xv, xmin, scale, &o8);
    *(u16x8*)(Ac + rb + IN_F + (size_t)i * 8) = o8;
}

// ---- kernel 4: pure bf16 GEMM, m97 structure (global_load_lds staging) ---
__global__ __launch_bounds__(256, 2)
void k_gemm2(const unsigned short* __restrict__ Ac, const unsigned short* __restrict__ Wc,
             float* __restrict__ out, int nmb) {
    __shared__ unsigned short As[BM * BK];   // 16 KB, linear row-major [128][64]
    __shared__ unsigned short Bs[BN * BK];

    const int t = threadIdx.x;
    const int lane = t & 63, w = t >> 6;

    // XCD-aware mapping: for nmb=64 M-panels, XCD x = bid&7 owns bM in
    // [x*8, x*8+8) across all 8 bN → per-XCD working set ~38 MB streamed,
    // K-stripe L2-resident across its 64 co-resident blocks.
    int bid = blockIdx.x;
    int bM, bN;
    if (nmb == 64) {
        int xcd = bid & 7, s = bid >> 3;
        bM = xcd * 8 + (s & 7);
        bN = s >> 3;
    } else {
        bM = bid >> 3;
        bN = bid & 7;
    }

    // staging source pointers: chunk idx = (q*4+w)*64 + lane; 16 B per lane
    const unsigned short* pa[4];
    const unsigned short* pb[4];
    #pragma unroll
    for (int q = 0; q < 4; ++q) {
        int idx = (q * 4 + w) * 64 + lane;
        int r = idx >> 3, c8 = idx & 7;
        pa[q] = Ac + (size_t)(bM * BM + r) * KDIM + c8 * 8;
        pb[q] = Wc + (size_t)(bN * BN + r) * KDIM + c8 * 8;
    }

    const int wr  = (w >> 1) * 64;
    const int wc2 = (w & 1) * 64;

    f32x4 acc[4][4] = {};

    for (int kt = 0; kt < KT; ++kt) {
        __syncthreads();
        #pragma unroll
        for (int q = 0; q < 4; ++q) {
            GLD16(pa[q], &As[(q * 4 + w) * 512]);
            GLD16(pb[q], &Bs[(q * 4 + w) * 512]);
            pa[q] += BK;
            pb[q] += BK;
        }
        __syncthreads();   // compiler emits vmcnt(0) drain here

        bf16x8 af[4][2];
        #pragma unroll
        for (int mi = 0; mi < 4; ++mi) {
            int row = wr + mi * 16 + (lane & 15);
            #pragma unroll
            for (int ks = 0; ks < 2; ++ks)
                af[mi][ks] = *(const bf16x8*)&As[row * BK + ks * 32 + (lane >> 4) * 8];
        }
        #pragma unroll
        for (int ni = 0; ni < 4; ++ni) {
            int col = wc2 + ni * 16 + (lane & 15);
            bf16x8 b0 = *(const bf16x8*)&Bs[col * BK + (lane >> 4) * 8];
            bf16x8 b1 = *(const bf16x8*)&Bs[col * BK + 32 + (lane >> 4) * 8];
            #pragma unroll
            for (int mi = 0; mi < 4; ++mi) {
                acc[mi][ni] = __builtin_amdgcn_mfma_f32_16x16x32_bf16(af[mi][0], b0, acc[mi][ni], 0, 0, 0);
                acc[mi][ni] = __builtin_amdgcn_mfma_f32_16x16x32_bf16(af[mi][1], b1, acc[mi][ni], 0, 0, 0);
            }
        }
    }

    #pragma unroll
    for (int mi = 0; mi < 4; ++mi) {
        #pragma unroll
        for (int ni = 0; ni < 4; ++ni) {
            #pragma unroll
            for (int reg = 0; reg < 4; ++reg) {
                int row = wr + mi * 16 + (lane >> 4) * 4 + reg;
                int col = wc2 + ni * 16 + (lane & 15);
                out[(size_t)(bM * BM + row) * OUT_F + bN * BN + col] = acc[mi][ni][reg];
            }
        }
    }
}

// ---- fallback fused GEMM (round-1 kernel, used if ws too small) ----------
__global__ __launch_bounds__(256, 2)
void k_gemm_fused(const float* __restrict__ x, const unsigned short* __restrict__ Wc,
                  const unsigned* __restrict__ mm, float* __restrict__ out) {
    __shared__ unsigned short As[BM * BK];
    __shared__ unsigned short Bs[BN * BK];

    const int t  = threadIdx.x;
    const int bM = blockIdx.x >> 3;
    const int bN = blockIdx.x & 7;

    const float xmax  = fkey_dec(mm[0]);
    const float xmin  = -fkey_dec(mm[1]);
    const float scale = 2.0f / (xmax - xmin + 1e-8f);

    const int lane = t & 63, wid = t >> 6;
    const int wr = (wid >> 1) * 64, wc = (wid & 1) * 64;

    const int rr = t >> 1, kh = t & 1;
    const float*          xrow = x  + (size_t)(bM * BM + rr) * IN_F;
    const unsigned short* wrow = Wc + (size_t)(bN * BN + rr) * KDIM;

    f32x4 acc[4][4] = {};

    for (int kt = 0; kt < KT; ++kt) {
        __syncthreads();
        {
            const u16x8* src = (const u16x8*)(wrow + kt * BK + kh * 32);
            #pragma unroll
            for (int q = 0; q < 4; ++q) {
                u16x8 v = src[q];
                int c = (kh * 4 + q) ^ (rr & 7);
                *(u16x8*)&Bs[rr * BK + c * 8] = v;
            }
        }
        if (kt < BASE_KT) {
            const float* xp = xrow + kt * BK + kh * 32;
            #pragma unroll
            for (int q = 0; q < 4; ++q) {
                float4 v0 = *(const float4*)(xp + q * 8);
                float4 v1 = *(const float4*)(xp + q * 8 + 4);
                u16x8 o8;
                o8[0] = bfr(silu_f(v0.x)); o8[1] = bfr(silu_f(v0.y));
                o8[2] = bfr(silu_f(v0.z)); o8[3] = bfr(silu_f(v0.w));
                o8[4] = bfr(silu_f(v1.x)); o8[5] = bfr(silu_f(v1.y));
                o8[6] = bfr(silu_f(v1.z)); o8[7] = bfr(silu_f(v1.w));
                int c = (kh * 4 + q) ^ (rr & 7);
                *(u16x8*)&As[rr * BK + c * 8] = o8;
            }
        } else {
            const int f0 = (kt - BASE_KT) * 8 + kh * 4;
            float4 v = *(const float4*)(xrow + f0);
            #pragma unroll
            for (int q = 0; q < 4; ++q) {
                float xv = (q == 0) ? v.x : (q == 1) ? v.y : (q == 2) ? v.z : v.w;
                u16x8 o8;
                spline8(xv, xmin, scale, &o8);
                int c = (kh * 4 + q) ^ (rr & 7);
                *(u16x8*)&As[rr * BK + c * 8] = o8;
            }
        }
        __syncthreads();

        bf16x8 af[4][2];
        #pragma unroll
        for (int mi = 0; mi < 4; ++mi) {
            int row = wr + mi * 16 + (lane & 15);
            int rb  = row & 7;
            #pragma unroll
            for (int ks = 0; ks < 2; ++ks) {
                int c = (ks * 4 + (lane >> 4)) ^ rb;
                af[mi][ks] = *(const bf16x8*)&As[row * BK + c * 8];
            }
        }
        #pragma unroll
        for (int ni = 0; ni < 4; ++ni) {
            int col = wc + ni * 16 + (lane & 15);
            int cb  = col & 7;
            bf16x8 b0 = *(const bf16x8*)&Bs[col * BK + (((lane >> 4)) ^ cb) * 8];
            bf16x8 b1 = *(const bf16x8*)&Bs[col * BK + ((4 + (lane >> 4)) ^ cb) * 8];
            #pragma unroll
            for (int mi = 0; mi < 4; ++mi) {
                acc[mi][ni] = __builtin_amdgcn_mfma_f32_16x16x32_bf16(af[mi][0], b0, acc[mi][ni], 0, 0, 0);
                acc[mi][ni] = __builtin_amdgcn_mfma_f32_16x16x32_bf16(af[mi][1], b1, acc[mi][ni], 0, 0, 0);
            }
        }
    }

    #pragma unroll
    for (int mi = 0; mi < 4; ++mi) {
        #pragma unroll
        for (int ni = 0; ni < 4; ++ni) {
            #pragma unroll
            for (int reg = 0; reg < 4; ++reg) {
                int row = wr + mi * 16 + (lane >> 4) * 4 + reg;
                int col = wc + ni * 16 + (lane & 15);
                out[(size_t)(bM * BM + row) * OUT_F + bN * BN + col] = acc[mi][ni][reg];
            }
        }
    }
}

// ---- launch --------------------------------------------------------------
extern "C" void kernel_launch(void* const* d_in, const int* in_sizes, int n_in,
                              void* d_out, int out_size, void* d_ws, size_t ws_size,
                              hipStream_t stream) {
    const float* x  = (const float*)d_in[0];
    const float* bw = (const float*)d_in[2];
    const float* sw = (const float*)d_in[3];
    const float* sc = (const float*)d_in[4];
    float* out = (float*)d_out;

    const int batch = in_sizes[0] / IN_F;   // 8192
    const int n4    = in_sizes[0] / 4;

    unsigned*       mm = (unsigned*)d_ws;
    unsigned short* Wc = (unsigned short*)((char*)d_ws + 512);
    const size_t    wc_bytes = (size_t)OUT_F * KDIM * 2;               // 18.9 MB
    unsigned short* Ac = (unsigned short*)((char*)d_ws + 512 + wc_bytes);
    const size_t    ac_bytes = (size_t)batch * KDIM * 2;               // 151 MB
    const size_t    need = 512 + wc_bytes + ac_bytes;

    hipMemsetAsync(d_ws, 0, 8, stream);
    k_minmax<<<1024, 256, 0, stream>>>(x, mm, n4);
    k_prepw<<<(OUT_F * IN_F) / 256, 256, 0, stream>>>(bw, sw, sc, Wc);

    if (ws_size >= need && (batch % BM) == 0) {
        k_build_a<<<(batch * IN_F) / 256, 256, 0, stream>>>(x, mm, Ac);
        int nmb = batch / BM;
        k_gemm2<<<dim3(nmb * (OUT_F / BN)), 256, 0, stream>>>(Ac, Wc, out, nmb);
    } else {
        k_gemm_fused<<<dim3((batch / BM) * (OUT_F / BN)), 256, 0, stream>>>(x, Wc, mm, out);
    }
}

// Round 3
// 336.339 us; speedup vs baseline: 1.5792x; 1.0935x over previous
//
#include <hip/hip_runtime.h>
#include <hip/hip_bf16.h>

#define IN_F   1024
#define OUT_F  1024
#define NBASIS 8
#define KDIM   (IN_F + IN_F * NBASIS)   // 9216
#define BK 64
#define KT      (KDIM / BK)             // 144
#define BASE_KT (IN_F / BK)             // 16

// ---- k_gemm3 geometry (8-phase-style, 2 phases/K-tile) --------------------
#define BM3 128
#define BN3 256
#define A_ELEMS (BM3 * BK)              // 8192 shorts (16 KB)
#define B_ELEMS (BN3 * BK)              // 16384 shorts (32 KB)
#define SLOT    (A_ELEMS + B_ELEMS)     // 24576 shorts (48 KB)
#define A_OFF   0
#define B_OFF   A_ELEMS

// ---- fallback geometry ----------------------------------------------------
#define BM 128
#define BN 128

typedef __attribute__((ext_vector_type(8))) short          bf16x8;
typedef __attribute__((ext_vector_type(8))) unsigned short u16x8;
typedef __attribute__((ext_vector_type(4))) float          f32x4;

typedef const __attribute__((address_space(1))) void gas_t;
typedef __attribute__((address_space(3))) void las_t;
#define GLD16(g, l) __builtin_amdgcn_global_load_lds((gas_t*)(g), (las_t*)(l), 16, 0, 0)

// ---- helpers -------------------------------------------------------------
__device__ __forceinline__ unsigned short bfr(float f) {
    unsigned u = __float_as_uint(f);
    unsigned r = (u + 0x7FFFu + ((u >> 16) & 1u)) >> 16;
    return (unsigned short)r;
}
__device__ __forceinline__ float silu_f(float v) { return v / (1.0f + __expf(-v)); }

__device__ __forceinline__ unsigned fkey(float f) {
    unsigned u = __float_as_uint(f);
    return u ^ ((u >> 31) ? 0xFFFFFFFFu : 0x80000000u);
}
__device__ __forceinline__ float fkey_dec(unsigned u) {
    unsigned b = (u >> 31) ? (u ^ 0x80000000u) : ~u;
    return __uint_as_float(b);
}

// spline basis (uniform cubic, closed form — validated rounds 1-2)
__device__ __forceinline__ void spline8(float xv, float xmin, float scale, u16x8* o8p) {
    float xn = (xv - xmin) * scale - 1.0f;
    float u  = (xn + 2.2f) * 2.5f;       // h=0.4, t0=-2.2
    int   iv = (int)floorf(u);
    iv = iv < 3 ? 3 : (iv > 7 ? 7 : iv);
    float tt = u - (float)iv;
    float s1 = 1.0f - tt;
    float t2 = tt * tt, t3 = t2 * tt;
    float n0 = s1 * s1 * s1 * (1.0f / 6.0f);
    float n1 = (3.0f * t3 - 6.0f * t2 + 4.0f) * (1.0f / 6.0f);
    float n2 = (-3.0f * t3 + 3.0f * t2 + 3.0f * tt + 1.0f) * (1.0f / 6.0f);
    float n3 = t3 * (1.0f / 6.0f);
    int j0 = iv - 3;
    u16x8 o8;
    #pragma unroll
    for (int s = 0; s < 8; ++s) {
        int d = s - j0;
        float val = (d == 0) ? n0 : (d == 1) ? n1 : (d == 2) ? n2 : (d == 3) ? n3 : 0.0f;
        o8[s] = bfr(val);
    }
    *o8p = o8;
}

// ---- kernel 1: global min/max of x --------------------------------------
__global__ void k_minmax(const float* __restrict__ x, unsigned* __restrict__ mm, int n4) {
    int tid    = blockIdx.x * blockDim.x + threadIdx.x;
    int stride = gridDim.x * blockDim.x;
    const float4* x4 = (const float4*)x;
    float mx  = -3.402823466e+38f;
    float mxn = -3.402823466e+38f;
    for (int i = tid; i < n4; i += stride) {
        float4 v = x4[i];
        mx  = fmaxf(mx,  fmaxf(fmaxf(v.x, v.y), fmaxf(v.z, v.w)));
        mxn = fmaxf(mxn, -fminf(fminf(v.x, v.y), fminf(v.z, v.w)));
    }
    #pragma unroll
    for (int off = 32; off; off >>= 1) {
        mx  = fmaxf(mx,  __shfl_down(mx,  off));
        mxn = fmaxf(mxn, __shfl_down(mxn, off));
    }
    __shared__ float smx[4], smn[4];
    int lane = threadIdx.x & 63, wid = threadIdx.x >> 6;
    if (lane == 0) { smx[wid] = mx; smn[wid] = mxn; }
    __syncthreads();
    if (threadIdx.x == 0) {
        #pragma unroll
        for (int w = 1; w < 4; ++w) { mx = fmaxf(mx, smx[w]); mxn = fmaxf(mxn, smn[w]); }
        atomicMax(&mm[0], fkey(mx));
        atomicMax(&mm[1], fkey(mxn));
    }
}

// ---- kernel 2: build combined bf16 weight Wc[OUT_F][KDIM] ----------------
__global__ void k_prepw(const float* __restrict__ bw, const float* __restrict__ sw,
                        const float* __restrict__ sc, unsigned short* __restrict__ Wc) {
    int t = blockIdx.x * blockDim.x + threadIdx.x;     // t = o*1024 + i
    int o = t >> 10, i = t & 1023;
    Wc[(size_t)o * KDIM + i] = bfr(bw[t]);
    float s = sc[t];
    const float4* swv = (const float4*)(sw + (size_t)t * 8);
    float4 a = swv[0], b = swv[1];
    u16x8 o8;
    o8[0] = bfr(a.x * s); o8[1] = bfr(a.y * s); o8[2] = bfr(a.z * s); o8[3] = bfr(a.w * s);
    o8[4] = bfr(b.x * s); o8[5] = bfr(b.y * s); o8[6] = bfr(b.z * s); o8[7] = bfr(b.w * s);
    *(u16x8*)(Wc + (size_t)o * KDIM + IN_F + i * 8) = o8;
}

// ---- kernel 3: build bf16 A-matrix Ac[batch][KDIM], 8 features/thread ----
__global__ void k_build_a(const float* __restrict__ x, const unsigned* __restrict__ mm,
                          unsigned short* __restrict__ Ac) {
    int t = blockIdx.x * blockDim.x + threadIdx.x;   // t = row*128 + i8
    int row = t >> 7, i8 = t & 127;
    const float xmax  = fkey_dec(mm[0]);
    const float xmin  = -fkey_dec(mm[1]);
    const float scale = 2.0f / (xmax - xmin + 1e-8f);
    const float* xp = x + (size_t)row * IN_F + i8 * 8;
    float4 v0 = *(const float4*)xp;
    float4 v1 = *(const float4*)(xp + 4);
    size_t rb = (size_t)row * KDIM;
    u16x8 sv;
    sv[0] = bfr(silu_f(v0.x)); sv[1] = bfr(silu_f(v0.y));
    sv[2] = bfr(silu_f(v0.z)); sv[3] = bfr(silu_f(v0.w));
    sv[4] = bfr(silu_f(v1.x)); sv[5] = bfr(silu_f(v1.y));
    sv[6] = bfr(silu_f(v1.z)); sv[7] = bfr(silu_f(v1.w));
    *(u16x8*)(Ac + rb + i8 * 8) = sv;
    unsigned short* bp = Ac + rb + IN_F + (size_t)i8 * 64;
    #pragma unroll
    for (int j = 0; j < 8; ++j) {
        float xv = (j == 0) ? v0.x : (j == 1) ? v0.y : (j == 2) ? v0.z : (j == 3) ? v0.w
                 : (j == 4) ? v1.x : (j == 5) ? v1.y : (j == 6) ? v1.z : v1.w;
        u16x8 o8;
        spline8(xv, xmin, scale, &o8);
        *(u16x8*)(bp + j * 8) = o8;
    }
}

#define MFMA(a, b, c) __builtin_amdgcn_mfma_f32_16x16x32_bf16((a), (b), (c), 0, 0, 0)

// ---- kernel 4: 2-phase counted-vmcnt GEMM, T2+T3+T4+T5 -------------------
// BM3=128 x BN3=256 tile, 8 waves (2M x 4N), triple-buffered LDS (144 KB),
// prefetch distance 2 K-tiles, steady-state wait = vmcnt(6) (1 tile in flight).
// T2: LDS linear (global_load_lds), source addrs pre-swizzled chunk^=(row&7),
// ds_reads apply the same XOR.
__global__ __launch_bounds__(512, 2)
void k_gemm3(const unsigned short* __restrict__ Ac, const unsigned short* __restrict__ Wc,
             float* __restrict__ out) {
    __shared__ unsigned short sm[3 * SLOT];   // 147456 B

    const int t    = threadIdx.x;
    const int lane = t & 63, w = t >> 6;      // w in [0,8)
    const int bid  = blockIdx.x;
    // XCD-aware: xcd = bid&7; each XCD gets 8 contiguous bM panels x all 4 bN
    const int xcd = bid & 7, s = bid >> 3;    // s in [0,32)
    const int bM  = xcd * 8 + (s & 7);        // [0,64)
    const int bN  = s >> 3;                   // [0,4)

    const int wave_r = w >> 2;                // A-half owner
    const int wcq    = w & 3;                 // B quarter owner

    // ---- staging source pointers (chunk-XOR pre-swizzled global addrs) ----
    const unsigned short* pa0; const unsigned short* pa1;
    const unsigned short* pb0; const unsigned short* pb1;
    const unsigned short* pb2; const unsigned short* pb3;
    {
        int L, r, c;
        L = (0 * 8 + w) * 64 + lane; r = L >> 3; c = L & 7;
        pa0 = Ac + (size_t)(bM * BM3 + r) * KDIM + (c ^ (r & 7)) * 8;
        L = (1 * 8 + w) * 64 + lane; r = L >> 3; c = L & 7;
        pa1 = Ac + (size_t)(bM * BM3 + r) * KDIM + (c ^ (r & 7)) * 8;
        L = (0 * 8 + w) * 64 + lane; r = L >> 3; c = L & 7;
        pb0 = Wc + (size_t)(bN * BN3 + r) * KDIM + (c ^ (r & 7)) * 8;
        L = (1 * 8 + w) * 64 + lane; r = L >> 3; c = L & 7;
        pb1 = Wc + (size_t)(bN * BN3 + r) * KDIM + (c ^ (r & 7)) * 8;
        L = (2 * 8 + w) * 64 + lane; r = L >> 3; c = L & 7;
        pb2 = Wc + (size_t)(bN * BN3 + r) * KDIM + (c ^ (r & 7)) * 8;
        L = (3 * 8 + w) * 64 + lane; r = L >> 3; c = L & 7;
        pb3 = Wc + (size_t)(bN * BN3 + r) * KDIM + (c ^ (r & 7)) * 8;
    }

    // ds_read chunk indices (XOR-swizzled), constant per lane
    const int ach0 = (lane >> 4) ^ (lane & 7);
    const int ach1 = ach0 ^ 4;
    const int l15  = lane & 15;

    f32x4 acc[4][4] = {};   // [mi][ni]

    // ---- prologue: stage tile 0 -> slot0, tile 1 -> slot1 ----
    GLD16(pa0, &sm[0 * SLOT + A_OFF + (0 * 8 + w) * 512]);
    GLD16(pa1, &sm[0 * SLOT + A_OFF + (1 * 8 + w) * 512]);
    GLD16(pb0, &sm[0 * SLOT + B_OFF + (0 * 8 + w) * 512]);
    GLD16(pb1, &sm[0 * SLOT + B_OFF + (1 * 8 + w) * 512]);
    GLD16(pb2, &sm[0 * SLOT + B_OFF + (2 * 8 + w) * 512]);
    GLD16(pb3, &sm[0 * SLOT + B_OFF + (3 * 8 + w) * 512]);
    pa0 += BK; pa1 += BK; pb0 += BK; pb1 += BK; pb2 += BK; pb3 += BK;
    GLD16(pa0, &sm[1 * SLOT + A_OFF + (0 * 8 + w) * 512]);
    GLD16(pa1, &sm[1 * SLOT + A_OFF + (1 * 8 + w) * 512]);
    GLD16(pb0, &sm[1 * SLOT + B_OFF + (0 * 8 + w) * 512]);
    GLD16(pb1, &sm[1 * SLOT + B_OFF + (1 * 8 + w) * 512]);
    GLD16(pb2, &sm[1 * SLOT + B_OFF + (2 * 8 + w) * 512]);
    GLD16(pb3, &sm[1 * SLOT + B_OFF + (3 * 8 + w) * 512]);
    pa0 += BK; pa1 += BK; pb0 += BK; pb1 += BK; pb2 += BK; pb3 += BK;

    int o0 = 0, o1 = SLOT, o2 = 2 * SLOT;   // slots: tile t, t+1, t+2
    int sk = 2;                              // next tile index to stage

    asm volatile("s_waitcnt vmcnt(6)" ::: "memory");   // tile 0 landed
    asm volatile("s_barrier" ::: "memory");

    for (int kt = 0; kt < KT; ++kt) {
        // ===== PHASE 1: all A frags + B frags ni=0,1; stage A(t+2) =====
        bf16x8 af[4][2];
        #pragma unroll
        for (int mi = 0; mi < 4; ++mi) {
            int r = wave_r * 64 + mi * 16 + l15;
            af[mi][0] = *(const bf16x8*)&sm[o0 + A_OFF + r * BK + ach0 * 8];
            af[mi][1] = *(const bf16x8*)&sm[o0 + A_OFF + r * BK + ach1 * 8];
        }
        bf16x8 bf0[2][2];
        #pragma unroll
        for (int ni = 0; ni < 2; ++ni) {
            int r = wcq * 64 + ni * 16 + l15;
            bf0[ni][0] = *(const bf16x8*)&sm[o0 + B_OFF + r * BK + ach0 * 8];
            bf0[ni][1] = *(const bf16x8*)&sm[o0 + B_OFF + r * BK + ach1 * 8];
        }
        GLD16(pa0, &sm[o2 + A_OFF + (0 * 8 + w) * 512]);
        GLD16(pa1, &sm[o2 + A_OFF + (1 * 8 + w) * 512]);
        __builtin_amdgcn_s_barrier();
        __builtin_amdgcn_s_setprio(1);
        #pragma unroll
        for (int ni = 0; ni < 2; ++ni)
            #pragma unroll
            for (int mi = 0; mi < 4; ++mi) {
                acc[mi][ni] = MFMA(af[mi][0], bf0[ni][0], acc[mi][ni]);
                acc[mi][ni] = MFMA(af[mi][1], bf0[ni][1], acc[mi][ni]);
            }
        __builtin_amdgcn_s_setprio(0);
        __builtin_amdgcn_s_barrier();

        // ===== PHASE 2: B frags ni=2,3 (A reused); stage B(t+2) =====
        bf16x8 bf1[2][2];
        #pragma unroll
        for (int ni = 0; ni < 2; ++ni) {
            int r = wcq * 64 + (ni + 2) * 16 + l15;
            bf1[ni][0] = *(const bf16x8*)&sm[o0 + B_OFF + r * BK + ach0 * 8];
            bf1[ni][1] = *(const bf16x8*)&sm[o0 + B_OFF + r * BK + ach1 * 8];
        }
        GLD16(pb0, &sm[o2 + B_OFF + (0 * 8 + w) * 512]);
        GLD16(pb1, &sm[o2 + B_OFF + (1 * 8 + w) * 512]);
        GLD16(pb2, &sm[o2 + B_OFF + (2 * 8 + w) * 512]);
        GLD16(pb3, &sm[o2 + B_OFF + (3 * 8 + w) * 512]);
        __builtin_amdgcn_s_barrier();
        __builtin_amdgcn_s_setprio(1);
        #pragma unroll
        for (int ni = 0; ni < 2; ++ni)
            #pragma unroll
            for (int mi = 0; mi < 4; ++mi) {
                acc[mi][ni + 2] = MFMA(af[mi][0], bf1[ni][0], acc[mi][ni + 2]);
                acc[mi][ni + 2] = MFMA(af[mi][1], bf1[ni][1], acc[mi][ni + 2]);
            }
        __builtin_amdgcn_s_setprio(0);

        // advance stage pointers (wrap past KT: redundant re-stage of tiles 0,1 — safe)
        pa0 += BK; pa1 += BK; pb0 += BK; pb1 += BK; pb2 += BK; pb3 += BK;
        if (++sk == KT) {
            sk = 0;
            pa0 -= KDIM; pa1 -= KDIM; pb0 -= KDIM; pb1 -= KDIM; pb2 -= KDIM; pb3 -= KDIM;
        }

        // ===== tile boundary: wait next tile's loads, rotate slots =====
        asm volatile("s_waitcnt vmcnt(6)" ::: "memory");
        asm volatile("s_barrier" ::: "memory");
        int tmp = o0; o0 = o1; o1 = o2; o2 = tmp;
    }

    // ---- epilogue ----
    #pragma unroll
    for (int mi = 0; mi < 4; ++mi) {
        #pragma unroll
        for (int ni = 0; ni < 4; ++ni) {
            #pragma unroll
            for (int reg = 0; reg < 4; ++reg) {
                int row = bM * BM3 + wave_r * 64 + mi * 16 + (lane >> 4) * 4 + reg;
                int col = bN * BN3 + wcq * 64 + ni * 16 + l15;
                out[(size_t)row * OUT_F + col] = acc[mi][ni][reg];
            }
        }
    }
}

// ---- fallback GEMM (round-2 validated m97 structure) ---------------------
__global__ __launch_bounds__(256, 2)
void k_gemm2(const unsigned short* __restrict__ Ac, const unsigned short* __restrict__ Wc,
             float* __restrict__ out, int nmb) {
    __shared__ unsigned short As[BM * BK];
    __shared__ unsigned short Bs[BN * BK];

    const int t = threadIdx.x;
    const int lane = t & 63, w = t >> 6;
    int bid = blockIdx.x;
    int bM = bid >> 3, bN = bid & 7;

    const unsigned short* pa[4];
    const unsigned short* pb[4];
    #pragma unroll
    for (int q = 0; q < 4; ++q) {
        int idx = (q * 4 + w) * 64 + lane;
        int r = idx >> 3, c8 = idx & 7;
        pa[q] = Ac + (size_t)(bM * BM + r) * KDIM + c8 * 8;
        pb[q] = Wc + (size_t)(bN * BN + r) * KDIM + c8 * 8;
    }

    const int wr  = (w >> 1) * 64;
    const int wc2 = (w & 1) * 64;

    f32x4 acc[4][4] = {};

    for (int kt = 0; kt < KT; ++kt) {
        __syncthreads();
        #pragma unroll
        for (int q = 0; q < 4; ++q) {
            GLD16(pa[q], &As[(q * 4 + w) * 512]);
            GLD16(pb[q], &Bs[(q * 4 + w) * 512]);
            pa[q] += BK;
            pb[q] += BK;
        }
        __syncthreads();

        bf16x8 af[4][2];
        #pragma unroll
        for (int mi = 0; mi < 4; ++mi) {
            int row = wr + mi * 16 + (lane & 15);
            #pragma unroll
            for (int ks = 0; ks < 2; ++ks)
                af[mi][ks] = *(const bf16x8*)&As[row * BK + ks * 32 + (lane >> 4) * 8];
        }
        #pragma unroll
        for (int ni = 0; ni < 4; ++ni) {
            int col = wc2 + ni * 16 + (lane & 15);
            bf16x8 b0 = *(const bf16x8*)&Bs[col * BK + (lane >> 4) * 8];
            bf16x8 b1 = *(const bf16x8*)&Bs[col * BK + 32 + (lane >> 4) * 8];
            #pragma unroll
            for (int mi = 0; mi < 4; ++mi) {
                acc[mi][ni] = MFMA(af[mi][0], b0, acc[mi][ni]);
                acc[mi][ni] = MFMA(af[mi][1], b1, acc[mi][ni]);
            }
        }
    }

    #pragma unroll
    for (int mi = 0; mi < 4; ++mi) {
        #pragma unroll
        for (int ni = 0; ni < 4; ++ni) {
            #pragma unroll
            for (int reg = 0; reg < 4; ++reg) {
                int row = wr + mi * 16 + (lane >> 4) * 4 + reg;
                int col = wc2 + ni * 16 + (lane & 15);
                out[(size_t)(bM * BM + row) * OUT_F + bN * BN + col] = acc[mi][ni][reg];
            }
        }
    }
}

// ---- launch --------------------------------------------------------------
extern "C" void kernel_launch(void* const* d_in, const int* in_sizes, int n_in,
                              void* d_out, int out_size, void* d_ws, size_t ws_size,
                              hipStream_t stream) {
    const float* x  = (const float*)d_in[0];
    const float* bw = (const float*)d_in[2];
    const float* sw = (const float*)d_in[3];
    const float* sc = (const float*)d_in[4];
    float* out = (float*)d_out;

    const int batch = in_sizes[0] / IN_F;   // 8192
    const int n4    = in_sizes[0] / 4;

    unsigned*       mm = (unsigned*)d_ws;
    unsigned short* Wc = (unsigned short*)((char*)d_ws + 512);
    const size_t    wc_bytes = (size_t)OUT_F * KDIM * 2;               // 18.9 MB
    unsigned short* Ac = (unsigned short*)((char*)d_ws + 512 + wc_bytes);
    const size_t    ac_bytes = (size_t)batch * KDIM * 2;               // 151 MB
    const size_t    need = 512 + wc_bytes + ac_bytes;

    hipMemsetAsync(d_ws, 0, 8, stream);
    k_minmax<<<1024, 256, 0, stream>>>(x, mm, n4);
    k_prepw<<<(OUT_F * IN_F) / 256, 256, 0, stream>>>(bw, sw, sc, Wc);

    if (ws_size >= need && batch == 8192) {
        k_build_a<<<(batch * 128) / 256, 256, 0, stream>>>(x, mm, Ac);
        k_gemm3<<<dim3((batch / BM3) * (OUT_F / BN3)), 512, 0, stream>>>(Ac, Wc, out);
    } else if (ws_size >= need && (batch % BM) == 0) {
        k_build_a<<<(batch * 128) / 256, 256, 0, stream>>>(x, mm, Ac);
        k_gemm2<<<dim3((batch / BM) * (OUT_F / BN)), 256, 0, stream>>>(Ac, Wc, out, batch / BM);
    }
}

// Round 4
// 319.917 us; speedup vs baseline: 1.6603x; 1.0513x over previous
//
#include <hip/hip_runtime.h>
#include <hip/hip_bf16.h>

#define IN_F   1024
#define OUT_F  1024
#define NBASIS 8
#define KDIM   (IN_F + IN_F * NBASIS)   // 9216
#define BK 64
#define KT      (KDIM / BK)             // 144

// ---- k_gemm4 geometry ----------------------------------------------------
#define BM3 128
#define BN3 256
#define A_ELEMS (BM3 * BK)              // 8192 shorts (16 KB)
#define B_ELEMS (BN3 * BK)              // 16384 shorts (32 KB)
#define SLOT    (A_ELEMS + B_ELEMS)     // 24576 shorts (48 KB)
#define A_OFF   0
#define B_OFF   A_ELEMS

// ---- fallback geometry ----------------------------------------------------
#define BM 128
#define BN 128

typedef __attribute__((ext_vector_type(8)))  short          bf16x8;
typedef __attribute__((ext_vector_type(8)))  unsigned short u16x8;
typedef __attribute__((ext_vector_type(4)))  float          f32x4;
typedef __attribute__((ext_vector_type(16))) float          f32x16;

typedef const __attribute__((address_space(1))) void gas_t;
typedef __attribute__((address_space(3))) void las_t;
#define GLD16(g, l) __builtin_amdgcn_global_load_lds((gas_t*)(g), (las_t*)(l), 16, 0, 0)

// ---- helpers -------------------------------------------------------------
__device__ __forceinline__ unsigned short bfr(float f) {
    unsigned u = __float_as_uint(f);
    unsigned r = (u + 0x7FFFu + ((u >> 16) & 1u)) >> 16;
    return (unsigned short)r;
}
__device__ __forceinline__ float silu_f(float v) { return v / (1.0f + __expf(-v)); }

__device__ __forceinline__ unsigned fkey(float f) {
    unsigned u = __float_as_uint(f);
    return u ^ ((u >> 31) ? 0xFFFFFFFFu : 0x80000000u);
}
__device__ __forceinline__ float fkey_dec(unsigned u) {
    unsigned b = (u >> 31) ? (u ^ 0x80000000u) : ~u;
    return __uint_as_float(b);
}

// spline basis (uniform cubic, closed form — validated rounds 1-3)
__device__ __forceinline__ void spline8(float xv, float xmin, float scale, u16x8* o8p) {
    float xn = (xv - xmin) * scale - 1.0f;
    float u  = (xn + 2.2f) * 2.5f;       // h=0.4, t0=-2.2
    int   iv = (int)floorf(u);
    iv = iv < 3 ? 3 : (iv > 7 ? 7 : iv);
    float tt = u - (float)iv;
    float s1 = 1.0f - tt;
    float t2 = tt * tt, t3 = t2 * tt;
    float n0 = s1 * s1 * s1 * (1.0f / 6.0f);
    float n1 = (3.0f * t3 - 6.0f * t2 + 4.0f) * (1.0f / 6.0f);
    float n2 = (-3.0f * t3 + 3.0f * t2 + 3.0f * tt + 1.0f) * (1.0f / 6.0f);
    float n3 = t3 * (1.0f / 6.0f);
    int j0 = iv - 3;
    u16x8 o8;
    #pragma unroll
    for (int s = 0; s < 8; ++s) {
        int d = s - j0;
        float val = (d == 0) ? n0 : (d == 1) ? n1 : (d == 2) ? n2 : (d == 3) ? n3 : 0.0f;
        o8[s] = bfr(val);
    }
    *o8p = o8;
}

// ---- kernel 1: global min/max of x --------------------------------------
__global__ void k_minmax(const float* __restrict__ x, unsigned* __restrict__ mm, int n4) {
    int tid    = blockIdx.x * blockDim.x + threadIdx.x;
    int stride = gridDim.x * blockDim.x;
    const float4* x4 = (const float4*)x;
    float mx  = -3.402823466e+38f;
    float mxn = -3.402823466e+38f;
    for (int i = tid; i < n4; i += stride) {
        float4 v = x4[i];
        mx  = fmaxf(mx,  fmaxf(fmaxf(v.x, v.y), fmaxf(v.z, v.w)));
        mxn = fmaxf(mxn, -fminf(fminf(v.x, v.y), fminf(v.z, v.w)));
    }
    #pragma unroll
    for (int off = 32; off; off >>= 1) {
        mx  = fmaxf(mx,  __shfl_down(mx,  off));
        mxn = fmaxf(mxn, __shfl_down(mxn, off));
    }
    __shared__ float smx[4], smn[4];
    int lane = threadIdx.x & 63, wid = threadIdx.x >> 6;
    if (lane == 0) { smx[wid] = mx; smn[wid] = mxn; }
    __syncthreads();
    if (threadIdx.x == 0) {
        #pragma unroll
        for (int w = 1; w < 4; ++w) { mx = fmaxf(mx, smx[w]); mxn = fmaxf(mxn, smn[w]); }
        atomicMax(&mm[0], fkey(mx));
        atomicMax(&mm[1], fkey(mxn));
    }
}

// ---- kernel 2: merged prep — build Ac AND Wc in one launch ---------------
// blocks [0, nba)        : Ac builder, 1 feature/thread (fully coalesced)
// blocks [nba, nba+4096) : Wc builder
__global__ void k_prep_all(const float* __restrict__ x, const unsigned* __restrict__ mm,
                           const float* __restrict__ bw, const float* __restrict__ sw,
                           const float* __restrict__ sc,
                           unsigned short* __restrict__ Ac, unsigned short* __restrict__ Wc,
                           int nba) {
    int bid = blockIdx.x;
    if (bid < nba) {
        // ---- Ac: t = row*1024 + i ----
        int t = bid * 256 + threadIdx.x;
        int row = t >> 10, i = t & 1023;
        const float xmax  = fkey_dec(mm[0]);
        const float xmin  = -fkey_dec(mm[1]);
        const float scale = 2.0f / (xmax - xmin + 1e-8f);
        float xv = x[t];
        size_t rb = (size_t)row * KDIM;
        Ac[rb + i] = bfr(silu_f(xv));          // 2B, lane-consecutive
        u16x8 o8;
        spline8(xv, xmin, scale, &o8);
        *(u16x8*)(Ac + rb + IN_F + (size_t)i * 8) = o8;   // 16B, lane-consecutive
    } else {
        // ---- Wc: t = o*1024 + i ----
        int t = (bid - nba) * 256 + threadIdx.x;
        int o = t >> 10, i = t & 1023;
        Wc[(size_t)o * KDIM + i] = bfr(bw[t]);
        float s = sc[t];
        const float4* swv = (const float4*)(sw + (size_t)t * 8);
        float4 a = swv[0], b = swv[1];
        u16x8 o8;
        o8[0] = bfr(a.x * s); o8[1] = bfr(a.y * s); o8[2] = bfr(a.z * s); o8[3] = bfr(a.w * s);
        o8[4] = bfr(b.x * s); o8[5] = bfr(b.y * s); o8[6] = bfr(b.z * s); o8[7] = bfr(b.w * s);
        *(u16x8*)(Wc + (size_t)o * KDIM + IN_F + i * 8) = o8;
    }
}

#define MFMA32(a, b, c) __builtin_amdgcn_mfma_f32_32x32x16_bf16((a), (b), (c), 0, 0, 0)
#define MFMA16(a, b, c) __builtin_amdgcn_mfma_f32_16x16x32_bf16((a), (b), (c), 0, 0, 0)

// ---- kernel 3: 2-phase counted-vmcnt GEMM, 32x32x16 MFMA -----------------
// BM3=128 x BN3=256, 8 waves (2M x 4N), each wave owns 64x64 = 2x2 of 32x32.
// Triple-buffered LDS (144 KB), prefetch 2 tiles, steady-state vmcnt(6).
// Phase split by K-half: each phase = 8 ds_read_b128 + GLDs + barrier +
// 8 MFMA(32x32x16) + barrier. T2 swizzle: linear LDS, pre-swizzled global src.
__global__ __launch_bounds__(512, 2)
void k_gemm4(const unsigned short* __restrict__ Ac, const unsigned short* __restrict__ Wc,
             float* __restrict__ out) {
    __shared__ unsigned short sm[3 * SLOT];   // 147456 B

    const int t    = threadIdx.x;
    const int lane = t & 63, w = t >> 6;
    const int bid  = blockIdx.x;
    const int xcd = bid & 7, s = bid >> 3;
    const int bM  = xcd * 8 + (s & 7);        // [0,64)
    const int bN  = s >> 3;                   // [0,4)

    const int wave_r = w >> 2;                // M-half (64 rows)
    const int wcq    = w & 3;                 // N-quarter (64 cols)
    const int l31 = lane & 31;
    const int hl  = lane >> 5;                // k-half within fragment

    // ---- staging source pointers (chunk-XOR pre-swizzled global addrs) ----
    const unsigned short* pa0; const unsigned short* pa1;
    const unsigned short* pb0; const unsigned short* pb1;
    const unsigned short* pb2; const unsigned short* pb3;
    {
        int L, r, c;
        L = (0 * 8 + w) * 64 + lane; r = L >> 3; c = L & 7;
        pa0 = Ac + (size_t)(bM * BM3 + r) * KDIM + (c ^ (r & 7)) * 8;
        L = (1 * 8 + w) * 64 + lane; r = L >> 3; c = L & 7;
        pa1 = Ac + (size_t)(bM * BM3 + r) * KDIM + (c ^ (r & 7)) * 8;
        L = (0 * 8 + w) * 64 + lane; r = L >> 3; c = L & 7;
        pb0 = Wc + (size_t)(bN * BN3 + r) * KDIM + (c ^ (r & 7)) * 8;
        L = (1 * 8 + w) * 64 + lane; r = L >> 3; c = L & 7;
        pb1 = Wc + (size_t)(bN * BN3 + r) * KDIM + (c ^ (r & 7)) * 8;
        L = (2 * 8 + w) * 64 + lane; r = L >> 3; c = L & 7;
        pb2 = Wc + (size_t)(bN * BN3 + r) * KDIM + (c ^ (r & 7)) * 8;
        L = (3 * 8 + w) * 64 + lane; r = L >> 3; c = L & 7;
        pb3 = Wc + (size_t)(bN * BN3 + r) * KDIM + (c ^ (r & 7)) * 8;
    }

    // fragment LDS address components (per-lane constants)
    // A row for mi: rA = wave_r*64 + mi*32 + l31 ; chunk = (kk*2+hl) ^ (rA&7)
    int rA[2], rB[2];
    #pragma unroll
    for (int mi = 0; mi < 2; ++mi) rA[mi] = wave_r * 64 + mi * 32 + l31;
    #pragma unroll
    for (int ni = 0; ni < 2; ++ni) rB[ni] = wcq * 64 + ni * 32 + l31;

    f32x16 acc[2][2] = {};

    // ---- prologue: stage tile 0 -> slot0, tile 1 -> slot1 ----
    GLD16(pa0, &sm[0 * SLOT + A_OFF + (0 * 8 + w) * 512]);
    GLD16(pa1, &sm[0 * SLOT + A_OFF + (1 * 8 + w) * 512]);
    GLD16(pb0, &sm[0 * SLOT + B_OFF + (0 * 8 + w) * 512]);
    GLD16(pb1, &sm[0 * SLOT + B_OFF + (1 * 8 + w) * 512]);
    GLD16(pb2, &sm[0 * SLOT + B_OFF + (2 * 8 + w) * 512]);
    GLD16(pb3, &sm[0 * SLOT + B_OFF + (3 * 8 + w) * 512]);
    pa0 += BK; pa1 += BK; pb0 += BK; pb1 += BK; pb2 += BK; pb3 += BK;
    GLD16(pa0, &sm[1 * SLOT + A_OFF + (0 * 8 + w) * 512]);
    GLD16(pa1, &sm[1 * SLOT + A_OFF + (1 * 8 + w) * 512]);
    GLD16(pb0, &sm[1 * SLOT + B_OFF + (0 * 8 + w) * 512]);
    GLD16(pb1, &sm[1 * SLOT + B_OFF + (1 * 8 + w) * 512]);
    GLD16(pb2, &sm[1 * SLOT + B_OFF + (2 * 8 + w) * 512]);
    GLD16(pb3, &sm[1 * SLOT + B_OFF + (3 * 8 + w) * 512]);
    pa0 += BK; pa1 += BK; pb0 += BK; pb1 += BK; pb2 += BK; pb3 += BK;

    int o0 = 0, o1 = SLOT, o2 = 2 * SLOT;
    int sk = 2;

    asm volatile("s_waitcnt vmcnt(6)" ::: "memory");
    asm volatile("s_barrier" ::: "memory");

    for (int kt = 0; kt < KT; ++kt) {
        // ===== PHASE 1: K-half kk=0,1 ; stage A(t+2) =====
        {
            bf16x8 a0[2], a1[2], b0[2], b1[2];
            #pragma unroll
            for (int mi = 0; mi < 2; ++mi) {
                int sa = rA[mi] & 7;
                a0[mi] = *(const bf16x8*)&sm[o0 + A_OFF + rA[mi] * BK + (((0 + hl) ^ sa) << 3)];
                a1[mi] = *(const bf16x8*)&sm[o0 + A_OFF + rA[mi] * BK + (((2 + hl) ^ sa) << 3)];
            }
            #pragma unroll
            for (int ni = 0; ni < 2; ++ni) {
                int sb = rB[ni] & 7;
                b0[ni] = *(const bf16x8*)&sm[o0 + B_OFF + rB[ni] * BK + (((0 + hl) ^ sb) << 3)];
                b1[ni] = *(const bf16x8*)&sm[o0 + B_OFF + rB[ni] * BK + (((2 + hl) ^ sb) << 3)];
            }
            GLD16(pa0, &sm[o2 + A_OFF + (0 * 8 + w) * 512]);
            GLD16(pa1, &sm[o2 + A_OFF + (1 * 8 + w) * 512]);
            __builtin_amdgcn_s_barrier();
            __builtin_amdgcn_s_setprio(1);
            #pragma unroll
            for (int mi = 0; mi < 2; ++mi)
                #pragma unroll
                for (int ni = 0; ni < 2; ++ni) {
                    acc[mi][ni] = MFMA32(a0[mi], b0[ni], acc[mi][ni]);
                    acc[mi][ni] = MFMA32(a1[mi], b1[ni], acc[mi][ni]);
                }
            __builtin_amdgcn_s_setprio(0);
            __builtin_amdgcn_s_barrier();
        }
        // ===== PHASE 2: K-half kk=2,3 ; stage B(t+2) =====
        {
            bf16x8 a0[2], a1[2], b0[2], b1[2];
            #pragma unroll
            for (int mi = 0; mi < 2; ++mi) {
                int sa = rA[mi] & 7;
                a0[mi] = *(const bf16x8*)&sm[o0 + A_OFF + rA[mi] * BK + (((4 + hl) ^ sa) << 3)];
                a1[mi] = *(const bf16x8*)&sm[o0 + A_OFF + rA[mi] * BK + (((6 + hl) ^ sa) << 3)];
            }
            #pragma unroll
            for (int ni = 0; ni < 2; ++ni) {
                int sb = rB[ni] & 7;
                b0[ni] = *(const bf16x8*)&sm[o0 + B_OFF + rB[ni] * BK + (((4 + hl) ^ sb) << 3)];
                b1[ni] = *(const bf16x8*)&sm[o0 + B_OFF + rB[ni] * BK + (((6 + hl) ^ sb) << 3)];
            }
            GLD16(pb0, &sm[o2 + B_OFF + (0 * 8 + w) * 512]);
            GLD16(pb1, &sm[o2 + B_OFF + (1 * 8 + w) * 512]);
            GLD16(pb2, &sm[o2 + B_OFF + (2 * 8 + w) * 512]);
            GLD16(pb3, &sm[o2 + B_OFF + (3 * 8 + w) * 512]);
            __builtin_amdgcn_s_barrier();
            __builtin_amdgcn_s_setprio(1);
            #pragma unroll
            for (int mi = 0; mi < 2; ++mi)
                #pragma unroll
                for (int ni = 0; ni < 2; ++ni) {
                    acc[mi][ni] = MFMA32(a0[mi], b0[ni], acc[mi][ni]);
                    acc[mi][ni] = MFMA32(a1[mi], b1[ni], acc[mi][ni]);
                }
            __builtin_amdgcn_s_setprio(0);
        }

        pa0 += BK; pa1 += BK; pb0 += BK; pb1 += BK; pb2 += BK; pb3 += BK;
        if (++sk == KT) {
            sk = 0;
            pa0 -= KDIM; pa1 -= KDIM; pb0 -= KDIM; pb1 -= KDIM; pb2 -= KDIM; pb3 -= KDIM;
        }

        asm volatile("s_waitcnt vmcnt(6)" ::: "memory");
        asm volatile("s_barrier" ::: "memory");
        int tmp = o0; o0 = o1; o1 = o2; o2 = tmp;
    }

    // ---- epilogue: 32x32 C/D layout col=lane&31, row=(reg&3)+8*(reg>>2)+4*(lane>>5)
    #pragma unroll
    for (int mi = 0; mi < 2; ++mi) {
        #pragma unroll
        for (int ni = 0; ni < 2; ++ni) {
            #pragma unroll
            for (int reg = 0; reg < 16; ++reg) {
                int row = bM * BM3 + wave_r * 64 + mi * 32 + (reg & 3) + 8 * (reg >> 2) + 4 * hl;
                int col = bN * BN3 + wcq * 64 + ni * 32 + l31;
                out[(size_t)row * OUT_F + col] = acc[mi][ni][reg];
            }
        }
    }
}

// ---- fallback GEMM (round-2 validated m97 structure, 16x16 MFMA) ---------
__global__ __launch_bounds__(256, 2)
void k_gemm2(const unsigned short* __restrict__ Ac, const unsigned short* __restrict__ Wc,
             float* __restrict__ out, int nmb) {
    __shared__ unsigned short As[BM * BK];
    __shared__ unsigned short Bs[BN * BK];

    const int t = threadIdx.x;
    const int lane = t & 63, w = t >> 6;
    int bid = blockIdx.x;
    int bM = bid >> 3, bN = bid & 7;

    const unsigned short* pa[4];
    const unsigned short* pb[4];
    #pragma unroll
    for (int q = 0; q < 4; ++q) {
        int idx = (q * 4 + w) * 64 + lane;
        int r = idx >> 3, c8 = idx & 7;
        pa[q] = Ac + (size_t)(bM * BM + r) * KDIM + c8 * 8;
        pb[q] = Wc + (size_t)(bN * BN + r) * KDIM + c8 * 8;
    }

    const int wr  = (w >> 1) * 64;
    const int wc2 = (w & 1) * 64;

    f32x4 acc[4][4] = {};

    for (int kt = 0; kt < KT; ++kt) {
        __syncthreads();
        #pragma unroll
        for (int q = 0; q < 4; ++q) {
            GLD16(pa[q], &As[(q * 4 + w) * 512]);
            GLD16(pb[q], &Bs[(q * 4 + w) * 512]);
            pa[q] += BK;
            pb[q] += BK;
        }
        __syncthreads();

        bf16x8 af[4][2];
        #pragma unroll
        for (int mi = 0; mi < 4; ++mi) {
            int row = wr + mi * 16 + (lane & 15);
            #pragma unroll
            for (int ks = 0; ks < 2; ++ks)
                af[mi][ks] = *(const bf16x8*)&As[row * BK + ks * 32 + (lane >> 4) * 8];
        }
        #pragma unroll
        for (int ni = 0; ni < 4; ++ni) {
            int col = wc2 + ni * 16 + (lane & 15);
            bf16x8 b0 = *(const bf16x8*)&Bs[col * BK + (lane >> 4) * 8];
            bf16x8 b1 = *(const bf16x8*)&Bs[col * BK + 32 + (lane >> 4) * 8];
            #pragma unroll
            for (int mi = 0; mi < 4; ++mi) {
                acc[mi][ni] = MFMA16(af[mi][0], b0, acc[mi][ni]);
                acc[mi][ni] = MFMA16(af[mi][1], b1, acc[mi][ni]);
            }
        }
    }

    #pragma unroll
    for (int mi = 0; mi < 4; ++mi) {
        #pragma unroll
        for (int ni = 0; ni < 4; ++ni) {
            #pragma unroll
            for (int reg = 0; reg < 4; ++reg) {
                int row = wr + mi * 16 + (lane >> 4) * 4 + reg;
                int col = wc2 + ni * 16 + (lane & 15);
                out[(size_t)(bM * BM + row) * OUT_F + bN * BN + col] = acc[mi][ni][reg];
            }
        }
    }
}

// ---- launch --------------------------------------------------------------
extern "C" void kernel_launch(void* const* d_in, const int* in_sizes, int n_in,
                              void* d_out, int out_size, void* d_ws, size_t ws_size,
                              hipStream_t stream) {
    const float* x  = (const float*)d_in[0];
    const float* bw = (const float*)d_in[2];
    const float* sw = (const float*)d_in[3];
    const float* sc = (const float*)d_in[4];
    float* out = (float*)d_out;

    const int batch = in_sizes[0] / IN_F;   // 8192
    const int n4    = in_sizes[0] / 4;

    unsigned*       mm = (unsigned*)d_ws;
    unsigned short* Wc = (unsigned short*)((char*)d_ws + 512);
    const size_t    wc_bytes = (size_t)OUT_F * KDIM * 2;               // 18.9 MB
    unsigned short* Ac = (unsigned short*)((char*)d_ws + 512 + wc_bytes);
    const size_t    ac_bytes = (size_t)batch * KDIM * 2;               // 151 MB
    const size_t    need = 512 + wc_bytes + ac_bytes;

    hipMemsetAsync(d_ws, 0, 8, stream);
    k_minmax<<<1024, 256, 0, stream>>>(x, mm, n4);

    const int nba = (batch * IN_F) / 256;   // Ac-builder blocks
    k_prep_all<<<nba + (OUT_F * IN_F) / 256, 256, 0, stream>>>(x, mm, bw, sw, sc, Ac, Wc, nba);

    if (ws_size >= need && batch == 8192) {
        k_gemm4<<<dim3((batch / BM3) * (OUT_F / BN3)), 512, 0, stream>>>(Ac, Wc, out);
    } else if (ws_size >= need && (batch % BM) == 0) {
        k_gemm2<<<dim3((batch / BM) * (OUT_F / BN)), 256, 0, stream>>>(Ac, Wc, out, batch / BM);
    }
}